// Round 5
// baseline (122.934 us; speedup 1.0000x reference)
//
#include <hip/hip_runtime.h>
#include <hip/hip_bf16.h>
#include <math.h>

// Dtype model (pinned R0-R4): float inputs f32; edge_index int32; d_out read
// as f32: chunk0 = pred f32[0:393216], chunk1 = yg f32[393216:786432]; np
// reference computed from bf16-cast inputs -> bf16 intermediates safe.
//
// R7: register spills kill. R9: strided us8 LDS reads = bank-conflict storm.
// R10: P[64x64]@X MFMA aggregation + transposed xs + prepacked W^T -> 127us.
// R11: fuse both GAT layers into one per-graph kernel, 5 launches -> 3. 119us.
// R12: logits folded into xl GEMMs as extra cols; 118.5us.
// R13 FAILED: cooperative grid.sync ~80us each -> banned. 286us.
// R14 FAILED: in-GEMM f32 W gather = latency storm -> prepack is worth its
//      launch; mlp self-pack fine. 151us.
// R15: prep shrunk to W-pack only; gat register-prefetches all W B-frags;
//      117.3us (best). Decomposition: fills ~83us floor, gat ~25us of which
//      ~90% is latency stall (8 serial phases, 2 waves/SIMD, 120cy LDS chains).
// R16 (this): gat 512 -> 1024 threads (16 waves, 4/SIMD). Every phase's
//      per-wave chain halves: L1 GEMM 14wx2tiles (was 7x4), L2 16x2(+logit),
//      aggs 4mw x 4cg x 2 tiles (was x2cg x 4). Same LDS, same arithmetic.
//      Expect gat ~25 -> ~15us, total ~108-111us.
//
// Race check: As2 k-pad zeroing must stay AFTER the L1 GEMM consumed As1
// (LDA1 reads overlap LDA2 pad addresses) -> stays in softmax spare threads.

#define N_NODES 16384
#define B_GRAPHS 256
#define K_NODES 64
#define DEG 8
#define NHEADS 4
#define C1 100
#define C2 128
#define IN_F 96
#define HID 64
#define OUT_SZ 24
#define PRED_ELEMS (K_NODES * B_GRAPHS * OUT_SZ)   // 393216
#define YG4 (PRED_ELEMS / 4)                       // 98304

#define W1T_ROWS 448   // 400 cols + 8 logit cols (400..407) padded to 7*64
#define W1T_K    96
#define W2T_ROWS 528   // 512 cols + 8 logit cols (512..519) padded to 33*16
#define W2T_K    128   // 100 padded

#define P1N  (W1T_ROWS * W1T_K)            // 43008
#define P2N  (W2T_ROWS * W2T_K)            // 67584

using bf16 = __hip_bfloat16;
typedef __attribute__((ext_vector_type(8))) short          frag_ab;  // 8 bf16
typedef __attribute__((ext_vector_type(4))) float          frag_cd;  // 4 f32
typedef unsigned short us8 __attribute__((ext_vector_type(8)));      // 16 B
typedef unsigned short us4 __attribute__((ext_vector_type(4)));      // 8 B

__device__ __forceinline__ float us2f(unsigned short u) {
  return __bfloat162float(__ushort_as_bfloat16(u));
}
__device__ __forceinline__ short f2bf_s(float f) {
  return __builtin_bit_cast(short, __float2bfloat16(f));
}

// ---------------------------------------------------------------------------
// prep: pack W1^T/W2^T (bf16, padded, k-contiguous) + fused attention
// projection cols (W·a_src / W·a_dst, float4-vectorized dots). 432 blocks.
// ---------------------------------------------------------------------------
__global__ __launch_bounds__(256)
void prep(const float* __restrict__ W1, const float* __restrict__ W2,
          const float* __restrict__ as1, const float* __restrict__ ad1,
          const float* __restrict__ as2, const float* __restrict__ ad2,
          bf16* __restrict__ W1t, bf16* __restrict__ W2t) {
  int idx = blockIdx.x * 256 + threadIdx.x;
  if (idx < P1N) {
    int c = idx / W1T_K, k = idx - c * W1T_K;
    float v = 0.f;
    if (c < 400) {
      v = W1[(size_t)k * 400 + c];
    } else if (c < 408) {
      int h = (c - 400) & 3;
      const float* wrow = W1 + (size_t)k * 400 + h * 100;
      const float* av   = ((c < 404) ? as1 : ad1) + h * 100;
      float s = 0.f;
#pragma unroll
      for (int q = 0; q < 100; q += 4) {
        float4 w4 = *(const float4*)(wrow + q);
        float4 a4 = *(const float4*)(av + q);
        s += w4.x * a4.x + w4.y * a4.y + w4.z * a4.z + w4.w * a4.w;
      }
      v = s;
    }
    W1t[idx] = __float2bfloat16(v);
  } else {
    int i2 = idx - P1N;
    int c = i2 >> 7, kk = i2 & 127;
    float v = 0.f;
    if (c < 512) {
      if (kk < 100) v = W2[(size_t)kk * 512 + c];
    } else if (c < 520 && kk < 100) {
      int h = (c - 512) & 3;
      const float* wrow = W2 + (size_t)kk * 512 + h * 128;
      const float* av   = ((c < 516) ? as2 : ad2) + h * 128;
      float s = 0.f;
#pragma unroll
      for (int q = 0; q < 128; q += 4) {
        float4 w4 = *(const float4*)(wrow + q);
        float4 a4 = *(const float4*)(av + q);
        s += w4.x * a4.x + w4.y * a4.y + w4.z * a4.z + w4.w * a4.w;
      }
      v = s;
    }
    W2t[i2] = __float2bfloat16(v);
  }
}

// ---------------------------------------------------------------------------
// Fused two-layer GAT, one block per graph (grid=256), 1024 threads
// (16 waves = 4/SIMD for latency hiding). All W B-fragments register-
// prefetched. Per-wave tile work halved vs the 512-thread version.
// ---------------------------------------------------------------------------
__global__ __launch_bounds__(1024)
void gat_fused(const float* __restrict__ x,
               const bf16* __restrict__ W1t, const bf16* __restrict__ W2t,
               const int* __restrict__ esrc,
               const float* __restrict__ b1, const float* __restrict__ b2,
               bf16* __restrict__ h2t) {
  constexpr int LDA1 = IN_F + 8;     // 104 (shorts)
  constexpr int LDA2 = 136;          // layer-2 A stride (K=128 + 8)
  constexpr int LDT  = 72;           // xs/Ps row stride (shorts)

  __shared__ __align__(16) short          As[64 * LDA2];          // 17.4 KB
  __shared__ __align__(16) unsigned short xs[W2T_ROWS * LDT];     // 76.0 KB
  __shared__ __align__(16) short          Ps[NHEADS * 64 * LDT];  // 36.9 KB
  __shared__ float bia1[C1], bia2[C2];
  __shared__ int   edg[K_NODES * DEG];

  const int g = blockIdx.x;
  const int t = threadIdx.x;
  const int wv = t >> 6;             // 0..15
  const int l  = t & 63;
  const int lm = l & 15;
  const int lk = (l >> 4) * 8;
  const int rq = (l >> 4) * 4;

  // ===== L1 B-frag prefetch (waves 0..13, 2 col-tiles each): issue FIRST
  // ===== so loads complete during the staging barrier's vmcnt drain.
  frag_ab bpre1[3][2];
  if (wv < 14) {
    const int n0 = wv * 32;
#pragma unroll
    for (int ksi = 0; ksi < 3; ++ksi)
#pragma unroll
      for (int nt = 0; nt < 2; ++nt)
        bpre1[ksi][nt] = *(const frag_ab*)((const short*)W1t +
                         (size_t)(n0 + nt * 16 + lm) * W1T_K + ksi * 32 + lk);
  }

  // ================= phase 0: stage =================
  {
    constexpr int QR = IN_F / 4;     // 24 float4 per row
    for (int idx = t; idx < 64 * QR; idx += 1024) {
      int m = idx / QR, q = idx - m * QR;
      const float4 v = *(const float4*)(x + ((size_t)(g * 64 + m) * IN_F + q * 4));
      short* d = &As[m * LDA1 + q * 4];
      d[0] = f2bf_s(v.x); d[1] = f2bf_s(v.y); d[2] = f2bf_s(v.z); d[3] = f2bf_s(v.w);
    }
  }
  if (t < C1) bia1[t] = b1[t];
  else if (t >= 128 && t < 128 + C2) bia2[t - 128] = b2[t - 128];
  if (t < K_NODES * DEG) edg[t] = esrc[g * K_NODES * DEG + t] & (K_NODES - 1);
  for (int idx = t; idx < NHEADS * 64 * LDT / 8; idx += 1024)
    *(us8*)&Ps[idx * 8] = (us8)0;
  __syncthreads();

  // ====== L1 phase 1: [xl1 | logits] = As @ W1t -> xs^T (waves 0..13) ======
  if (wv < 14) {
    const int n0 = wv * 32;
    frag_cd acc[4][2] = {};
#pragma unroll
    for (int ksi = 0; ksi < 3; ++ksi) {
#pragma unroll
      for (int mt = 0; mt < 4; ++mt) {
        frag_ab a = *(const frag_ab*)&As[(mt * 16 + lm) * LDA1 + ksi * 32 + lk];
#pragma unroll
        for (int nt = 0; nt < 2; ++nt)
          acc[mt][nt] = __builtin_amdgcn_mfma_f32_16x16x32_bf16(a, bpre1[ksi][nt],
                                                                acc[mt][nt], 0, 0, 0);
      }
    }
#pragma unroll
    for (int mt = 0; mt < 4; ++mt)
#pragma unroll
      for (int nt = 0; nt < 2; ++nt) {
        const int c4 = n0 + nt * 16 + lm;
        us4 o;
#pragma unroll
        for (int r = 0; r < 4; ++r) o[r] = (unsigned short)f2bf_s(acc[mt][nt][r]);
        *(us4*)&xs[c4 * LDT + mt * 16 + rq] = o;
      }
  }

  // ===== L2 B-frag prefetch (all 16 waves, 2 tiles each; wave 0 + logit
  // ===== tile): latency absorbed by the coming softmax + agg phases.
  frag_ab bpre2[4][2];
  frag_ab blpre[4];
  {
    const int n0 = wv * 32;
#pragma unroll
    for (int ksi = 0; ksi < 4; ++ksi)
#pragma unroll
      for (int nt = 0; nt < 2; ++nt)
        bpre2[ksi][nt] = *(const frag_ab*)((const short*)W2t +
                         (size_t)(n0 + nt * 16 + lm) * W2T_K + ksi * 32 + lk);
    if (wv == 0)
#pragma unroll
      for (int ksi = 0; ksi < 4; ++ksi)
        blpre[ksi] = *(const frag_ab*)((const short*)W2t +
                     (size_t)(512 + lm) * W2T_K + ksi * 32 + lk);
  }
  __syncthreads();

  // ====== L1 phase 2: softmax -> Ps; spare threads zero As2 k-pads ======
  if (t < 256) {
    const int n = t >> 2, h = t & 3;
    const float ad = us2f(xs[(404 + h) * LDT + n]);
    int   sv[9];
    float a[9];
#pragma unroll
    for (int j = 0; j < 8; ++j) sv[j] = edg[n * DEG + j];
    sv[8] = n;
#pragma unroll
    for (int j = 0; j < 9; ++j) {
      float v = us2f(xs[(400 + h) * LDT + sv[j]]) + ad;
      a[j] = (v >= 0.f) ? v : 0.2f * v;       // leaky_relu 0.2
    }
    float m = -1e30f;
#pragma unroll
    for (int j = 0; j < 9; ++j) m = fmaxf(m, a[j]);
    float s = 0.f;
#pragma unroll
    for (int j = 0; j < 9; ++j) { a[j] = __expf(a[j] - m); s += a[j]; }
    const float inv = 1.f / (s + 1e-16f);
    short* prow = &Ps[(h * 64 + n) * LDT];
#pragma unroll
    for (int j = 0; j < 9; ++j) {
      float tw = a[j];
#pragma unroll
      for (int i = 0; i < 9; ++i)
        if (i != j && sv[i] == sv[j]) tw += a[i];
      prow[sv[j]] = f2bf_s(tw * inv);         // idempotent dedupe
    }
  } else {
    // zero As layer-2 k-padding (k = 100..127); As1 is dead here
    for (int i = t - 256; i < 64 * 28; i += 768) {
      int m = i / 28, kk = 100 + (i - m * 28);
      As[m * LDA2 + kk] = 0;
    }
  }
  __syncthreads();

  // ====== L1 phase 3: h1 = 0.25*sum_h P_h @ X_h + bias, ELU -> As2 ======
  // 16 waves = 4 m-tiles x 4 col-groups; NT=7 tiles split 2+2+2+1.
  {
    const int mw  = (wv & 3) * 16;
    const int cg2 = wv >> 2;
    const int ntb = cg2 * 2;
    const int nte = (cg2 == 3) ? 7 : ntb + 2;
    frag_cd acc[2] = {};
#pragma unroll
    for (int h = 0; h < NHEADS; ++h)
#pragma unroll
      for (int ks = 0; ks < 64; ks += 32) {
        frag_ab a = *(const frag_ab*)&Ps[(h * 64 + mw + lm) * LDT + ks + lk];
        for (int nt = ntb; nt < nte; ++nt) {
          frag_ab b = *(const frag_ab*)&xs[(h * C1 + nt * 16 + lm) * LDT + ks + lk];
          acc[nt - ntb] = __builtin_amdgcn_mfma_f32_16x16x32_bf16(a, b,
                                                                  acc[nt - ntb], 0, 0, 0);
      }
    }
    for (int nt = ntb; nt < nte; ++nt) {
      const int c = nt * 16 + lm;
      if (c < C1) {
        const float bc = bia1[c];
#pragma unroll
        for (int r = 0; r < 4; ++r) {
          float vv = acc[nt - ntb][r] * 0.25f + bc;
          vv = (vv > 0.f) ? vv : (__expf(vv) - 1.f);   // ELU
          As[(mw + rq + r) * LDA2 + c] = f2bf_s(vv);
        }
      }
    }
  }
  __syncthreads();

  // ====== L2 phase 1: xl2 = As @ W2t -> xs^T; wave 0 adds logit tile ======
  {
    const int n0 = wv * 32;
    frag_cd acc[4][2] = {};
    frag_cd accL[4] = {};
#pragma unroll
    for (int ksi = 0; ksi < 4; ++ksi) {
#pragma unroll
      for (int mt = 0; mt < 4; ++mt) {
        frag_ab a = *(const frag_ab*)&As[(mt * 16 + lm) * LDA2 + ksi * 32 + lk];
#pragma unroll
        for (int nt = 0; nt < 2; ++nt)
          acc[mt][nt] = __builtin_amdgcn_mfma_f32_16x16x32_bf16(a, bpre2[ksi][nt],
                                                                acc[mt][nt], 0, 0, 0);
        if (wv == 0)
          accL[mt] = __builtin_amdgcn_mfma_f32_16x16x32_bf16(a, blpre[ksi],
                                                             accL[mt], 0, 0, 0);
      }
    }
#pragma unroll
    for (int mt = 0; mt < 4; ++mt)
#pragma unroll
      for (int nt = 0; nt < 2; ++nt) {
        const int c4 = n0 + nt * 16 + lm;
        us4 o;
#pragma unroll
        for (int r = 0; r < 4; ++r) o[r] = (unsigned short)f2bf_s(acc[mt][nt][r]);
        *(us4*)&xs[c4 * LDT + mt * 16 + rq] = o;
      }
    if (wv == 0) {
#pragma unroll
      for (int mt = 0; mt < 4; ++mt) {
        us4 o;
#pragma unroll
        for (int r = 0; r < 4; ++r) o[r] = (unsigned short)f2bf_s(accL[mt][r]);
        *(us4*)&xs[(512 + lm) * LDT + mt * 16 + rq] = o;
      }
    }
  }
  __syncthreads();

  // ====== L2 phase 2: softmax -> Ps (same nonzero support; no re-zero) ======
  if (t < 256) {
    const int n = t >> 2, h = t & 3;
    const float ad = us2f(xs[(516 + h) * LDT + n]);
    int   sv[9];
    float a[9];
#pragma unroll
    for (int j = 0; j < 8; ++j) sv[j] = edg[n * DEG + j];
    sv[8] = n;
#pragma unroll
    for (int j = 0; j < 9; ++j) {
      float v = us2f(xs[(512 + h) * LDT + sv[j]]) + ad;
      a[j] = (v >= 0.f) ? v : 0.2f * v;
    }
    float m = -1e30f;
#pragma unroll
    for (int j = 0; j < 9; ++j) m = fmaxf(m, a[j]);
    float s = 0.f;
#pragma unroll
    for (int j = 0; j < 9; ++j) { a[j] = __expf(a[j] - m); s += a[j]; }
    const float inv = 1.f / (s + 1e-16f);
    short* prow = &Ps[(h * 64 + n) * LDT];
#pragma unroll
    for (int j = 0; j < 9; ++j) {
      float tw = a[j];
#pragma unroll
      for (int i = 0; i < 9; ++i)
        if (i != j && sv[i] == sv[j]) tw += a[i];
      prow[sv[j]] = f2bf_s(tw * inv);
    }
  }
  __syncthreads();

  // ====== L2 phase 3: h2 = 0.25*sum_h P_h @ X_h + bias -> h2t[k][b][c] ======
  // 16 waves = 4 m-tiles x 4 col-groups x 2 tiles (NT=8).
  {
    const int mw  = (wv & 3) * 16;
    const int ntb = (wv >> 2) * 2;
    frag_cd acc[2] = {};
#pragma unroll
    for (int h = 0; h < NHEADS; ++h)
#pragma unroll
      for (int ks = 0; ks < 64; ks += 32) {
        frag_ab a = *(const frag_ab*)&Ps[(h * 64 + mw + lm) * LDT + ks + lk];
#pragma unroll
        for (int nt = 0; nt < 2; ++nt) {
          frag_ab b = *(const frag_ab*)&xs[(h * C2 + (ntb + nt) * 16 + lm) * LDT + ks + lk];
          acc[nt] = __builtin_amdgcn_mfma_f32_16x16x32_bf16(a, b, acc[nt], 0, 0, 0);
        }
      }
    unsigned short* outp = (unsigned short*)h2t;
#pragma unroll
    for (int nt = 0; nt < 2; ++nt) {
      const int c = (ntb + nt) * 16 + lm;
      const float bc = bia2[c];
#pragma unroll
      for (int r = 0; r < 4; ++r) {
        float vv = acc[nt][r] * 0.25f + bc;
        outp[((size_t)(mw + rq + r) * B_GRAPHS + g) * C2 + c] =
            (unsigned short)f2bf_s(vv);
      }
    }
  }
}

// ---------------------------------------------------------------------------
// MFMA MLP head (R14/R15 verified): self-sufficient. Per-block LDS bf16 pack
// of fw1[k]/fw2[k], A-frags direct from global h2t, yg grid-stride.
// Grid 256 = (k) x (ms), 256 threads.
// ---------------------------------------------------------------------------
__global__ __launch_bounds__(256)
void mlp_mfma(const bf16* __restrict__ h2t,
              const float* __restrict__ fw1, const float* __restrict__ fb1,
              const float* __restrict__ fw2, const float* __restrict__ fb2,
              const float* __restrict__ y,
              float* __restrict__ yg, float* __restrict__ pred) {
  constexpr int LDB1 = C2 + 8;   // 136
  constexpr int LDB2 = HID + 8;  // 72
  constexpr int LDH  = HID + 8;  // 72
  __shared__ __align__(16) short B1[HID * LDB1];   // 17.4 KB
  __shared__ __align__(16) short B2[32 * LDB2];    // 4.6 KB
  __shared__ __align__(16) short Hs[64 * LDH];     // 9.2 KB

  const int k  = blockIdx.x & 63;
  const int ms = blockIdx.x >> 6;
  const int t  = threadIdx.x;
  const int wv = t >> 6;
  const int l  = t & 63;
  const int lm = l & 15;
  const int lk = (l >> 4) * 8;
  const int rq = (l >> 4) * 4;

  const unsigned short* A = (const unsigned short*)h2t +
                            ((size_t)k * B_GRAPHS + ms * 64) * C2;

  // issue A-frag loads early (independent of LDS pack)
  frag_ab a_pre[4];
#pragma unroll
  for (int ksi = 0; ksi < 4; ++ksi)
    a_pre[ksi] = *(const frag_ab*)(A + (size_t)(wv * 16 + lm) * C2 + ksi * 32 + lk);

  // pack fw1[k] (128x64 f32) -> B1[n][kk] bf16; fw2[k] (64x24) -> B2[n][kk]
  for (int idx = t; idx < C2 * HID; idx += 256) {
    int kk = idx >> 6, n = idx & 63;
    B1[n * LDB1 + kk] = f2bf_s(fw1[(size_t)k * (C2 * HID) + idx]);
  }
  for (int idx = t; idx < HID * 32; idx += 256) {
    int kk = idx >> 5, n = idx & 31;
    B2[n * LDB2 + kk] = f2bf_s(
        (n < OUT_SZ) ? fw2[(size_t)k * (HID * OUT_SZ) + kk * OUT_SZ + n] : 0.f);
  }
  // yg = float(bf16(y)) grid-stride (independent of everything)
  for (int j = blockIdx.x * 256 + t; j < YG4; j += 256 * 256) {
    int i = j * 4;
    float4 v = *(const float4*)(y + i);
    v.x = __bfloat162float(__float2bfloat16(v.x));
    v.y = __bfloat162float(__float2bfloat16(v.y));
    v.z = __bfloat162float(__float2bfloat16(v.z));
    v.w = __bfloat162float(__float2bfloat16(v.w));
    *(float4*)(yg + i) = v;
  }
  __syncthreads();

  frag_cd acc[4] = {};
#pragma unroll
  for (int ksi = 0; ksi < 4; ++ksi) {
#pragma unroll
    for (int nt = 0; nt < 4; ++nt) {
      frag_ab b = *(const frag_ab*)&B1[(nt * 16 + lm) * LDB1 + ksi * 32 + lk];
      acc[nt] = __builtin_amdgcn_mfma_f32_16x16x32_bf16(a_pre[ksi], b, acc[nt], 0, 0, 0);
    }
  }
#pragma unroll
  for (int nt = 0; nt < 4; ++nt) {
    const int j  = nt * 16 + lm;
    const float bj = fb1[k * HID + j];
#pragma unroll
    for (int r = 0; r < 4; ++r) {
      const int m = wv * 16 + rq + r;
      Hs[m * LDH + j] = f2bf_s(fmaxf(acc[nt][r] + bj, 0.f));
    }
  }
  __syncthreads();

  frag_cd acc2[2] = {};
#pragma unroll
  for (int ks = 0; ks < HID; ks += 32) {
    frag_ab a = *(const frag_ab*)&Hs[(wv * 16 + lm) * LDH + ks + lk];
#pragma unroll
    for (int nt = 0; nt < 2; ++nt) {
      frag_ab b = *(const frag_ab*)&B2[(nt * 16 + lm) * LDB2 + ks + lk];
      acc2[nt] = __builtin_amdgcn_mfma_f32_16x16x32_bf16(a, b, acc2[nt], 0, 0, 0);
    }
  }
#pragma unroll
  for (int nt = 0; nt < 2; ++nt) {
    const int q = nt * 16 + lm;
    if (q < OUT_SZ) {
      const float bq = fb2[k * OUT_SZ + q];
#pragma unroll
      for (int r = 0; r < 4; ++r) {
        const int m = wv * 16 + rq + r;
        pred[((size_t)k * B_GRAPHS + ms * 64 + m) * OUT_SZ + q] = acc2[nt][r] + bq;
      }
    }
  }
}

// ---------------------------------------------------------------------------
extern "C" void kernel_launch(void* const* d_in, const int* in_sizes, int n_in,
                              void* d_out, int out_size, void* d_ws, size_t ws_size,
                              hipStream_t stream) {
  const float* x   = (const float*)d_in[0];
  const int*   ei  = (const int*)d_in[1];    // [2,E]: first E entries = src
  const float* y   = (const float*)d_in[3];
  const float* W1  = (const float*)d_in[4];
  const float* as1 = (const float*)d_in[5];
  const float* ad1 = (const float*)d_in[6];
  const float* b1  = (const float*)d_in[7];
  const float* W2  = (const float*)d_in[8];
  const float* as2 = (const float*)d_in[9];
  const float* ad2 = (const float*)d_in[10];
  const float* b2  = (const float*)d_in[11];
  const float* fw1 = (const float*)d_in[12];
  const float* fb1 = (const float*)d_in[13];
  const float* fw2 = (const float*)d_in[14];
  const float* fb2 = (const float*)d_in[15];

  // Workspace: h2t, W1t, W2t  (~4.2 MB)
  bf16* h2t = (bf16*)d_ws;
  bf16* W1t = h2t + (size_t)N_NODES * C2;
  bf16* W2t = W1t + P1N;

  float* out  = (float*)d_out;
  float* pred = out;
  float* yg   = out + PRED_ELEMS;

  // ---- prep: pack W^T (+ fused attention-projection cols) ----
  prep<<<(P1N + P2N) / 256, 256, 0, stream>>>(W1, W2, as1, ad1, as2, ad2,
                                              W1t, W2t);

  // ---- fused two-layer GAT (16 waves/block, register-prefetched W) ----
  gat_fused<<<B_GRAPHS, 1024, 0, stream>>>(x, W1t, W2t, ei, b1, b2, h2t);

  // ---- MFMA MLP head (self-packing) + yg -> d_out ----
  mlp_mfma<<<K_NODES * 4, 256, 0, stream>>>(h2t, fw1, fb1, fw2, fb2, y,
                                            yg, pred);
}

// Round 6
// 115.915 us; speedup vs baseline: 1.0606x; 1.0606x over previous
//
#include <hip/hip_runtime.h>
#include <hip/hip_bf16.h>
#include <math.h>

// Dtype model (pinned R0-R4): float inputs f32; edge_index int32; d_out read
// as f32: chunk0 = pred f32[0:393216], chunk1 = yg f32[393216:786432]; np
// reference computed from bf16-cast inputs -> bf16 intermediates safe.
//
// R7: register spills kill. R9: strided us8 LDS reads = bank-conflict storm.
// R10: P[64x64]@X MFMA aggregation + transposed xs + prepacked W^T -> 127us.
// R11: fuse both GAT layers into one per-graph kernel, 5 launches -> 3. 119us.
// R12: logits folded into xl GEMMs as extra cols; 118.5us.
// R13 FAILED: cooperative grid.sync ~80us each -> banned. 286us.
// R14 FAILED: in-GEMM f32 W gather = latency storm -> prepack worth its
//      launch; mlp self-pack fine. 151us.
// R15: prep = W-pack only; gat register-prefetches all W B-frags. 117.3 (best).
// R16 FAILED: 1024 threads/block (16 waves): slower barriers + thinner MFMA
//      tiles beat the TLP gain in a barrier-phased 1-block/CU kernel. 122.9.
// R17 (this): exact R15 revert + one micro-fix: stage phase As writes were
//      4x scalar ds_write_u16 per float4 -> single 8B us4 store (3 LDS writes
//      per thread instead of 12). Decomposition: ~82us harness fills (268MB
//      poison @82% HBM peak) + ~20us launch gaps (node count proven minimal:
//      R13/R14 + cross-block gat->mlp dep) + ~10us kernels. If this lands
//      >=117, kernels are << floor -> roofline.
//
// Race check: As2 k-pad zeroing must stay AFTER the L1 GEMM consumed As1
// (LDA1 reads overlap LDA2 pad addresses) -> stays in softmax spare threads.

#define N_NODES 16384
#define B_GRAPHS 256
#define K_NODES 64
#define DEG 8
#define NHEADS 4
#define C1 100
#define C2 128
#define IN_F 96
#define HID 64
#define OUT_SZ 24
#define PRED_ELEMS (K_NODES * B_GRAPHS * OUT_SZ)   // 393216
#define YG4 (PRED_ELEMS / 4)                       // 98304

#define W1T_ROWS 448   // 400 cols + 8 logit cols (400..407) padded to 7*64
#define W1T_K    96
#define W2T_ROWS 528   // 512 cols + 8 logit cols (512..519) padded to 33*16
#define W2T_K    128   // 100 padded

#define P1N  (W1T_ROWS * W1T_K)            // 43008
#define P2N  (W2T_ROWS * W2T_K)            // 67584

using bf16 = __hip_bfloat16;
typedef __attribute__((ext_vector_type(8))) short          frag_ab;  // 8 bf16
typedef __attribute__((ext_vector_type(4))) float          frag_cd;  // 4 f32
typedef unsigned short us8 __attribute__((ext_vector_type(8)));      // 16 B
typedef unsigned short us4 __attribute__((ext_vector_type(4)));      // 8 B

__device__ __forceinline__ float us2f(unsigned short u) {
  return __bfloat162float(__ushort_as_bfloat16(u));
}
__device__ __forceinline__ short f2bf_s(float f) {
  return __builtin_bit_cast(short, __float2bfloat16(f));
}

// ---------------------------------------------------------------------------
// prep: pack W1^T/W2^T (bf16, padded, k-contiguous) + fused attention
// projection cols (W·a_src / W·a_dst, float4-vectorized dots). 432 blocks.
// ---------------------------------------------------------------------------
__global__ __launch_bounds__(256)
void prep(const float* __restrict__ W1, const float* __restrict__ W2,
          const float* __restrict__ as1, const float* __restrict__ ad1,
          const float* __restrict__ as2, const float* __restrict__ ad2,
          bf16* __restrict__ W1t, bf16* __restrict__ W2t) {
  int idx = blockIdx.x * 256 + threadIdx.x;
  if (idx < P1N) {
    int c = idx / W1T_K, k = idx - c * W1T_K;
    float v = 0.f;
    if (c < 400) {
      v = W1[(size_t)k * 400 + c];
    } else if (c < 408) {
      int h = (c - 400) & 3;
      const float* wrow = W1 + (size_t)k * 400 + h * 100;
      const float* av   = ((c < 404) ? as1 : ad1) + h * 100;
      float s = 0.f;
#pragma unroll
      for (int q = 0; q < 100; q += 4) {
        float4 w4 = *(const float4*)(wrow + q);
        float4 a4 = *(const float4*)(av + q);
        s += w4.x * a4.x + w4.y * a4.y + w4.z * a4.z + w4.w * a4.w;
      }
      v = s;
    }
    W1t[idx] = __float2bfloat16(v);
  } else {
    int i2 = idx - P1N;
    int c = i2 >> 7, kk = i2 & 127;
    float v = 0.f;
    if (c < 512) {
      if (kk < 100) v = W2[(size_t)kk * 512 + c];
    } else if (c < 520 && kk < 100) {
      int h = (c - 512) & 3;
      const float* wrow = W2 + (size_t)kk * 512 + h * 128;
      const float* av   = ((c < 516) ? as2 : ad2) + h * 128;
      float s = 0.f;
#pragma unroll
      for (int q = 0; q < 128; q += 4) {
        float4 w4 = *(const float4*)(wrow + q);
        float4 a4 = *(const float4*)(av + q);
        s += w4.x * a4.x + w4.y * a4.y + w4.z * a4.z + w4.w * a4.w;
      }
      v = s;
    }
    W2t[i2] = __float2bfloat16(v);
  }
}

// ---------------------------------------------------------------------------
// Fused two-layer GAT, one block per graph (grid=256), 512 threads (8 waves).
// All W B-fragments register-prefetched: L1 frags at kernel start (complete
// during staging barrier's vmcnt drain), L2 frags after L1 GEMM (complete
// during softmax/agg). GEMM phases are pure LDS-read + MFMA.
// ---------------------------------------------------------------------------
__global__ __launch_bounds__(512)
void gat_fused(const float* __restrict__ x,
               const bf16* __restrict__ W1t, const bf16* __restrict__ W2t,
               const int* __restrict__ esrc,
               const float* __restrict__ b1, const float* __restrict__ b2,
               bf16* __restrict__ h2t) {
  constexpr int LDA1 = IN_F + 8;     // 104 (shorts)
  constexpr int LDA2 = 136;          // layer-2 A stride (K=128 + 8)
  constexpr int LDT  = 72;           // xs/Ps row stride (shorts)

  __shared__ __align__(16) short          As[64 * LDA2];          // 17.4 KB
  __shared__ __align__(16) unsigned short xs[W2T_ROWS * LDT];     // 76.0 KB
  __shared__ __align__(16) short          Ps[NHEADS * 64 * LDT];  // 36.9 KB
  __shared__ float bia1[C1], bia2[C2];
  __shared__ int   edg[K_NODES * DEG];

  const int g = blockIdx.x;
  const int t = threadIdx.x;
  const int wv = t >> 6;
  const int l  = t & 63;
  const int lm = l & 15;
  const int lk = (l >> 4) * 8;
  const int rq = (l >> 4) * 4;

  // ===== L1 B-frag prefetch: issue FIRST so loads complete during the =====
  // ===== staging barrier's vmcnt drain (no stall in the L1 GEMM).     =====
  frag_ab bpre1[3][4];
  if (wv < 7) {
    const int n0 = wv * 64;
#pragma unroll
    for (int ksi = 0; ksi < 3; ++ksi)
#pragma unroll
      for (int nt = 0; nt < 4; ++nt)
        bpre1[ksi][nt] = *(const frag_ab*)((const short*)W1t +
                         (size_t)(n0 + nt * 16 + lm) * W1T_K + ksi * 32 + lk);
  }

  // ================= phase 0: stage =================
  {
    constexpr int QR = IN_F / 4;     // 24 float4 per row
    for (int idx = t; idx < 64 * QR; idx += 512) {
      int m = idx / QR, q = idx - m * QR;
      const float4 v = *(const float4*)(x + ((size_t)(g * 64 + m) * IN_F + q * 4));
      us4 o;
      o[0] = (unsigned short)f2bf_s(v.x); o[1] = (unsigned short)f2bf_s(v.y);
      o[2] = (unsigned short)f2bf_s(v.z); o[3] = (unsigned short)f2bf_s(v.w);
      *(us4*)&As[m * LDA1 + q * 4] = o;    // 8B aligned: 208B rows, 8B offsets
    }
  }
  if (t < C1) bia1[t] = b1[t];
  else if (t >= 128 && t < 128 + C2) bia2[t - 128] = b2[t - 128];
  if (t < K_NODES * DEG) edg[t] = esrc[g * K_NODES * DEG + t] & (K_NODES - 1);
  for (int idx = t; idx < NHEADS * 64 * LDT / 8; idx += 512)
    *(us8*)&Ps[idx * 8] = (us8)0;
  __syncthreads();

  // ====== L1 phase 1: [xl1 | logits] = As @ W1t -> xs^T (waves 0..6) ======
  if (wv < 7) {
    const int n0 = wv * 64;
    frag_cd acc[4][4] = {};
#pragma unroll
    for (int ksi = 0; ksi < 3; ++ksi) {
#pragma unroll
      for (int mt = 0; mt < 4; ++mt) {
        frag_ab a = *(const frag_ab*)&As[(mt * 16 + lm) * LDA1 + ksi * 32 + lk];
#pragma unroll
        for (int nt = 0; nt < 4; ++nt)
          acc[mt][nt] = __builtin_amdgcn_mfma_f32_16x16x32_bf16(a, bpre1[ksi][nt],
                                                                acc[mt][nt], 0, 0, 0);
      }
    }
#pragma unroll
    for (int mt = 0; mt < 4; ++mt)
#pragma unroll
      for (int nt = 0; nt < 4; ++nt) {
        const int c4 = n0 + nt * 16 + lm;
        us4 o;
#pragma unroll
        for (int r = 0; r < 4; ++r) o[r] = (unsigned short)f2bf_s(acc[mt][nt][r]);
        *(us4*)&xs[c4 * LDT + mt * 16 + rq] = o;
      }
  }

  // ===== L2 B-frag prefetch: issue now; latency absorbed by the coming =====
  // ===== softmax + aggregation phases (vmcnt drained at next barrier). =====
  frag_ab bpre2[4][4];
  frag_ab blpre[4];
  {
    const int n0 = wv * 64;
#pragma unroll
    for (int ksi = 0; ksi < 4; ++ksi)
#pragma unroll
      for (int nt = 0; nt < 4; ++nt)
        bpre2[ksi][nt] = *(const frag_ab*)((const short*)W2t +
                         (size_t)(n0 + nt * 16 + lm) * W2T_K + ksi * 32 + lk);
    if (wv == 0)
#pragma unroll
      for (int ksi = 0; ksi < 4; ++ksi)
        blpre[ksi] = *(const frag_ab*)((const short*)W2t +
                     (size_t)(512 + lm) * W2T_K + ksi * 32 + lk);
  }
  __syncthreads();

  // ====== L1 phase 2: softmax -> Ps; spare threads zero As2 k-pads ======
  if (t < 256) {
    const int n = t >> 2, h = t & 3;
    const float ad = us2f(xs[(404 + h) * LDT + n]);
    int   sv[9];
    float a[9];
#pragma unroll
    for (int j = 0; j < 8; ++j) sv[j] = edg[n * DEG + j];
    sv[8] = n;
#pragma unroll
    for (int j = 0; j < 9; ++j) {
      float v = us2f(xs[(400 + h) * LDT + sv[j]]) + ad;
      a[j] = (v >= 0.f) ? v : 0.2f * v;       // leaky_relu 0.2
    }
    float m = -1e30f;
#pragma unroll
    for (int j = 0; j < 9; ++j) m = fmaxf(m, a[j]);
    float s = 0.f;
#pragma unroll
    for (int j = 0; j < 9; ++j) { a[j] = __expf(a[j] - m); s += a[j]; }
    const float inv = 1.f / (s + 1e-16f);
    short* prow = &Ps[(h * 64 + n) * LDT];
#pragma unroll
    for (int j = 0; j < 9; ++j) {
      float tw = a[j];
#pragma unroll
      for (int i = 0; i < 9; ++i)
        if (i != j && sv[i] == sv[j]) tw += a[i];
      prow[sv[j]] = f2bf_s(tw * inv);         // idempotent dedupe
    }
  } else {
    // zero As layer-2 k-padding (k = 100..127); As1 is dead here
    for (int i = t - 256; i < 64 * 28; i += 256) {
      int m = i / 28, kk = 100 + (i - m * 28);
      As[m * LDA2 + kk] = 0;
    }
  }
  __syncthreads();

  // ====== L1 phase 3: h1 = 0.25*sum_h P_h @ X_h + bias, ELU -> As2 ======
  {
    const int mw = (wv & 3) * 16;
    const int cg2 = wv >> 2;
    const int ntb = cg2 * 4;
    const int nte = (cg2 == 0) ? 4 : 7;        // NT=7 tiles split 4+3
    frag_cd acc[4] = {};
#pragma unroll
    for (int h = 0; h < NHEADS; ++h)
#pragma unroll
      for (int ks = 0; ks < 64; ks += 32) {
        frag_ab a = *(const frag_ab*)&Ps[(h * 64 + mw + lm) * LDT + ks + lk];
        for (int nt = ntb; nt < nte; ++nt) {
          frag_ab b = *(const frag_ab*)&xs[(h * C1 + nt * 16 + lm) * LDT + ks + lk];
          acc[nt - ntb] = __builtin_amdgcn_mfma_f32_16x16x32_bf16(a, b,
                                                                  acc[nt - ntb], 0, 0, 0);
      }
    }
    for (int nt = ntb; nt < nte; ++nt) {
      const int c = nt * 16 + lm;
      if (c < C1) {
        const float bc = bia1[c];
#pragma unroll
        for (int r = 0; r < 4; ++r) {
          float vv = acc[nt - ntb][r] * 0.25f + bc;
          vv = (vv > 0.f) ? vv : (__expf(vv) - 1.f);   // ELU
          As[(mw + rq + r) * LDA2 + c] = f2bf_s(vv);
        }
      }
    }
  }
  __syncthreads();

  // ====== L2 phase 1: xl2 = As @ W2t -> xs^T; wave 0 adds logit tile ======
  {
    const int n0 = wv * 64;
    frag_cd acc[4][4] = {};
    frag_cd accL[4] = {};
#pragma unroll
    for (int ksi = 0; ksi < 4; ++ksi) {
#pragma unroll
      for (int mt = 0; mt < 4; ++mt) {
        frag_ab a = *(const frag_ab*)&As[(mt * 16 + lm) * LDA2 + ksi * 32 + lk];
#pragma unroll
        for (int nt = 0; nt < 4; ++nt)
          acc[mt][nt] = __builtin_amdgcn_mfma_f32_16x16x32_bf16(a, bpre2[ksi][nt],
                                                                acc[mt][nt], 0, 0, 0);
        if (wv == 0)
          accL[mt] = __builtin_amdgcn_mfma_f32_16x16x32_bf16(a, blpre[ksi],
                                                             accL[mt], 0, 0, 0);
      }
    }
#pragma unroll
    for (int mt = 0; mt < 4; ++mt)
#pragma unroll
      for (int nt = 0; nt < 4; ++nt) {
        const int c4 = n0 + nt * 16 + lm;
        us4 o;
#pragma unroll
        for (int r = 0; r < 4; ++r) o[r] = (unsigned short)f2bf_s(acc[mt][nt][r]);
        *(us4*)&xs[c4 * LDT + mt * 16 + rq] = o;
      }
    if (wv == 0) {
#pragma unroll
      for (int mt = 0; mt < 4; ++mt) {
        us4 o;
#pragma unroll
        for (int r = 0; r < 4; ++r) o[r] = (unsigned short)f2bf_s(accL[mt][r]);
        *(us4*)&xs[(512 + lm) * LDT + mt * 16 + rq] = o;
      }
    }
  }
  __syncthreads();

  // ====== L2 phase 2: softmax -> Ps (same nonzero support; no re-zero) ======
  if (t < 256) {
    const int n = t >> 2, h = t & 3;
    const float ad = us2f(xs[(516 + h) * LDT + n]);
    int   sv[9];
    float a[9];
#pragma unroll
    for (int j = 0; j < 8; ++j) sv[j] = edg[n * DEG + j];
    sv[8] = n;
#pragma unroll
    for (int j = 0; j < 9; ++j) {
      float v = us2f(xs[(512 + h) * LDT + sv[j]]) + ad;
      a[j] = (v >= 0.f) ? v : 0.2f * v;
    }
    float m = -1e30f;
#pragma unroll
    for (int j = 0; j < 9; ++j) m = fmaxf(m, a[j]);
    float s = 0.f;
#pragma unroll
    for (int j = 0; j < 9; ++j) { a[j] = __expf(a[j] - m); s += a[j]; }
    const float inv = 1.f / (s + 1e-16f);
    short* prow = &Ps[(h * 64 + n) * LDT];
#pragma unroll
    for (int j = 0; j < 9; ++j) {
      float tw = a[j];
#pragma unroll
      for (int i = 0; i < 9; ++i)
        if (i != j && sv[i] == sv[j]) tw += a[i];
      prow[sv[j]] = f2bf_s(tw * inv);
    }
  }
  __syncthreads();

  // ====== L2 phase 3: h2 = 0.25*sum_h P_h @ X_h + bias -> h2t[k][b][c] ======
  {
    const int mw = (wv & 3) * 16;
    const int cg2 = wv >> 2;
    const int ntb = cg2 * 4;                    // NT=8 split 4+4
    frag_cd acc[4] = {};
#pragma unroll
    for (int h = 0; h < NHEADS; ++h)
#pragma unroll
      for (int ks = 0; ks < 64; ks += 32) {
        frag_ab a = *(const frag_ab*)&Ps[(h * 64 + mw + lm) * LDT + ks + lk];
#pragma unroll
        for (int nt = 0; nt < 4; ++nt) {
          frag_ab b = *(const frag_ab*)&xs[(h * C2 + (ntb + nt) * 16 + lm) * LDT + ks + lk];
          acc[nt] = __builtin_amdgcn_mfma_f32_16x16x32_bf16(a, b, acc[nt], 0, 0, 0);
        }
      }
    unsigned short* outp = (unsigned short*)h2t;
#pragma unroll
    for (int nt = 0; nt < 4; ++nt) {
      const int c = (ntb + nt) * 16 + lm;
      const float bc = bia2[c];
#pragma unroll
      for (int r = 0; r < 4; ++r) {
        float vv = acc[nt][r] * 0.25f + bc;
        outp[((size_t)(mw + rq + r) * B_GRAPHS + g) * C2 + c] =
            (unsigned short)f2bf_s(vv);
      }
    }
  }
}

// ---------------------------------------------------------------------------
// MFMA MLP head (R14/R15 verified): self-sufficient. Per-block LDS bf16 pack
// of fw1[k]/fw2[k], A-frags direct from global h2t, yg grid-stride.
// Grid 256 = (k) x (ms), 256 threads.
// ---------------------------------------------------------------------------
__global__ __launch_bounds__(256)
void mlp_mfma(const bf16* __restrict__ h2t,
              const float* __restrict__ fw1, const float* __restrict__ fb1,
              const float* __restrict__ fw2, const float* __restrict__ fb2,
              const float* __restrict__ y,
              float* __restrict__ yg, float* __restrict__ pred) {
  constexpr int LDB1 = C2 + 8;   // 136
  constexpr int LDB2 = HID + 8;  // 72
  constexpr int LDH  = HID + 8;  // 72
  __shared__ __align__(16) short B1[HID * LDB1];   // 17.4 KB
  __shared__ __align__(16) short B2[32 * LDB2];    // 4.6 KB
  __shared__ __align__(16) short Hs[64 * LDH];     // 9.2 KB

  const int k  = blockIdx.x & 63;
  const int ms = blockIdx.x >> 6;
  const int t  = threadIdx.x;
  const int wv = t >> 6;
  const int l  = t & 63;
  const int lm = l & 15;
  const int lk = (l >> 4) * 8;
  const int rq = (l >> 4) * 4;

  const unsigned short* A = (const unsigned short*)h2t +
                            ((size_t)k * B_GRAPHS + ms * 64) * C2;

  // issue A-frag loads early (independent of LDS pack)
  frag_ab a_pre[4];
#pragma unroll
  for (int ksi = 0; ksi < 4; ++ksi)
    a_pre[ksi] = *(const frag_ab*)(A + (size_t)(wv * 16 + lm) * C2 + ksi * 32 + lk);

  // pack fw1[k] (128x64 f32) -> B1[n][kk] bf16; fw2[k] (64x24) -> B2[n][kk]
  for (int idx = t; idx < C2 * HID; idx += 256) {
    int kk = idx >> 6, n = idx & 63;
    B1[n * LDB1 + kk] = f2bf_s(fw1[(size_t)k * (C2 * HID) + idx]);
  }
  for (int idx = t; idx < HID * 32; idx += 256) {
    int kk = idx >> 5, n = idx & 31;
    B2[n * LDB2 + kk] = f2bf_s(
        (n < OUT_SZ) ? fw2[(size_t)k * (HID * OUT_SZ) + kk * OUT_SZ + n] : 0.f);
  }
  // yg = float(bf16(y)) grid-stride (independent of everything)
  for (int j = blockIdx.x * 256 + t; j < YG4; j += 256 * 256) {
    int i = j * 4;
    float4 v = *(const float4*)(y + i);
    v.x = __bfloat162float(__float2bfloat16(v.x));
    v.y = __bfloat162float(__float2bfloat16(v.y));
    v.z = __bfloat162float(__float2bfloat16(v.z));
    v.w = __bfloat162float(__float2bfloat16(v.w));
    *(float4*)(yg + i) = v;
  }
  __syncthreads();

  frag_cd acc[4] = {};
#pragma unroll
  for (int ksi = 0; ksi < 4; ++ksi) {
#pragma unroll
    for (int nt = 0; nt < 4; ++nt) {
      frag_ab b = *(const frag_ab*)&B1[(nt * 16 + lm) * LDB1 + ksi * 32 + lk];
      acc[nt] = __builtin_amdgcn_mfma_f32_16x16x32_bf16(a_pre[ksi], b, acc[nt], 0, 0, 0);
    }
  }
#pragma unroll
  for (int nt = 0; nt < 4; ++nt) {
    const int j  = nt * 16 + lm;
    const float bj = fb1[k * HID + j];
#pragma unroll
    for (int r = 0; r < 4; ++r) {
      const int m = wv * 16 + rq + r;
      Hs[m * LDH + j] = f2bf_s(fmaxf(acc[nt][r] + bj, 0.f));
    }
  }
  __syncthreads();

  frag_cd acc2[2] = {};
#pragma unroll
  for (int ks = 0; ks < HID; ks += 32) {
    frag_ab a = *(const frag_ab*)&Hs[(wv * 16 + lm) * LDH + ks + lk];
#pragma unroll
    for (int nt = 0; nt < 2; ++nt) {
      frag_ab b = *(const frag_ab*)&B2[(nt * 16 + lm) * LDB2 + ks + lk];
      acc2[nt] = __builtin_amdgcn_mfma_f32_16x16x32_bf16(a, b, acc2[nt], 0, 0, 0);
    }
  }
#pragma unroll
  for (int nt = 0; nt < 2; ++nt) {
    const int q = nt * 16 + lm;
    if (q < OUT_SZ) {
      const float bq = fb2[k * OUT_SZ + q];
#pragma unroll
      for (int r = 0; r < 4; ++r) {
        const int m = wv * 16 + rq + r;
        pred[((size_t)k * B_GRAPHS + ms * 64 + m) * OUT_SZ + q] = acc2[nt][r] + bq;
      }
    }
  }
}

// ---------------------------------------------------------------------------
extern "C" void kernel_launch(void* const* d_in, const int* in_sizes, int n_in,
                              void* d_out, int out_size, void* d_ws, size_t ws_size,
                              hipStream_t stream) {
  const float* x   = (const float*)d_in[0];
  const int*   ei  = (const int*)d_in[1];    // [2,E]: first E entries = src
  const float* y   = (const float*)d_in[3];
  const float* W1  = (const float*)d_in[4];
  const float* as1 = (const float*)d_in[5];
  const float* ad1 = (const float*)d_in[6];
  const float* b1  = (const float*)d_in[7];
  const float* W2  = (const float*)d_in[8];
  const float* as2 = (const float*)d_in[9];
  const float* ad2 = (const float*)d_in[10];
  const float* b2  = (const float*)d_in[11];
  const float* fw1 = (const float*)d_in[12];
  const float* fb1 = (const float*)d_in[13];
  const float* fw2 = (const float*)d_in[14];
  const float* fb2 = (const float*)d_in[15];

  // Workspace: h2t, W1t, W2t  (~4.2 MB)
  bf16* h2t = (bf16*)d_ws;
  bf16* W1t = h2t + (size_t)N_NODES * C2;
  bf16* W2t = W1t + P1N;

  float* out  = (float*)d_out;
  float* pred = out;
  float* yg   = out + PRED_ELEMS;

  // ---- prep: pack W^T (+ fused attention-projection cols) ----
  prep<<<(P1N + P2N) / 256, 256, 0, stream>>>(W1, W2, as1, ad1, as2, ad2,
                                              W1t, W2t);

  // ---- fused two-layer GAT (register-prefetched W) -> h2t ----
  gat_fused<<<B_GRAPHS, 512, 0, stream>>>(x, W1t, W2t, ei, b1, b2, h2t);

  // ---- MFMA MLP head (self-packing) + yg -> d_out ----
  mlp_mfma<<<K_NODES * 4, 256, 0, stream>>>(h2t, fw1, fb1, fw2, fb2, y,
                                            yg, pred);
}